// Round 19
// baseline (10745.543 us; speedup 1.0000x reference)
//
#include <hip/hip_runtime.h>
#include <cstdio>
#include <cstdint>

// V=30000, E=512, H=512, T=32, B=64, L=512
// eg layout: [t][e4:128][b:64][4]   (64 MB)
// h  layout: [t][c2:256][b:64][2]   (64 MB per dir)
// em layout: [t][b][tag]            (4 MB)
// wpack: [dir][wg:256][ks:8][sec:2][kc:16][r:8][j:4]  (16 MB)
// R19 = wave-specialized step pipeline (T16 pattern). Block 512 = 8 waves:
//   waves 0-3: h-waves. Wave sl handles k in [128sl,128sl+128): poll its 64
//     producer WGs' flags, cached h loads, pk-fma h-dot w/ LDS weights,
//     write partb[s&1][sl].
//   waves 4-7: e-waves. Wave sl handles e-k in [128sl,+128): e-dot for step
//     s+1 AFTER the barrier (global uniform weights; fully off the chain);
//     write partb[s&1][4+sl] at top of step from last iteration's eacc.
//   waves 4-5 additionally: gates+cstate+h-store+flag. lane l -> (colL=l&1,
//     b=l>>1); flat store offset == l -> each wave stores 256 contiguous B.
//   ONE barrier per step; partb double-buffered (hazard-free, see derivation).
// sync: flg[dir][step][wg][half:2]; producer wave4/5 lane {0,64} sets its
//   half after vmcnt(0) drain of the wave's 64 dword sc1 stores. Consumer
//   h-wave lane b polls the int64 (both halves) of producer wg'=64*sl+b.

typedef float f32x4 __attribute__((ext_vector_type(4)));
typedef float f32x2 __attribute__((ext_vector_type(2)));

#define PKFMA(ACC, W2, H2) \
    asm("v_pk_fma_f32 %0, %1, %2, %0" : "+v"(ACC) : "v"(W2), "v"(H2))

// ---------------------------------------------------------------------------
// K0: embedding gather -> eg[t][e4][b][4]
// ---------------------------------------------------------------------------
__global__ __launch_bounds__(512) void k_gather(
    const int* __restrict__ x, const float* __restrict__ emb,
    float4* __restrict__ eg4)
{
    const int t   = blockIdx.x;
    const int tid = threadIdx.x;
    __shared__ int xv[64];
    if (tid < 64) xv[tid] = x[tid * 512 + t];
    __syncthreads();
    #pragma unroll
    for (int i = 0; i < 16; ++i) {
        const int flat = i * 512 + tid;       // 0..8191
        const int b  = flat & 63;
        const int e4 = flat >> 6;             // 0..127
        const float4 v = *reinterpret_cast<const float4*>(
            emb + (size_t)xv[b] * 512 + e4 * 4);
        eg4[((size_t)t * 128 + e4) * 64 + b] = v;
    }
}

// ---------------------------------------------------------------------------
// K0b: pack weights: [dir][wg:256][ks:8][sec:2][kc:16][r:8][j:4]
// ---------------------------------------------------------------------------
__global__ __launch_bounds__(256) void k_pack(
    const float* __restrict__ wih_f, const float* __restrict__ whh_f,
    const float* __restrict__ wih_b, const float* __restrict__ whh_b,
    float* __restrict__ wpack)
{
    const int i = blockIdx.x * 256 + threadIdx.x;   // 0 .. 4194303
    const int j   = i & 3;
    const int r   = (i >> 2) & 7;
    const int kc  = (i >> 5) & 15;
    const int sec = (i >> 9) & 1;
    const int ks  = (i >> 10) & 7;
    const int wg  = (i >> 13) & 255;
    const int dir = (i >> 21) & 1;
    const int k   = ks * 64 + kc * 4 + j;           // 0..511
    const int g   = r >> 1, colL = r & 1;
    const int rg  = g * 512 + wg * 2 + colL;        // global gate row
    const float* wih = dir ? wih_b : wih_f;
    const float* whh = dir ? whh_b : whh_f;
    const float v = sec ? whh[(size_t)rg * 512 + k] : wih[(size_t)rg * 512 + k];
    wpack[i] = v;
}

// ---------------------------------------------------------------------------
// e-dot: 128-k slice, 4 chunks of 32 k. Global uniform weights (off-chain).
// ---------------------------------------------------------------------------
__device__ __forceinline__ void edot128(
    const float4* __restrict__ eg4, const float* __restrict__ wpackbase,
    const int t, const int sl, const int b, f32x2 eacc2[8])
{
    #pragma unroll
    for (int r = 0; r < 8; ++r) eacc2[r] = (f32x2){0.f, 0.f};
    #pragma unroll
    for (int c = 0; c < 4; ++c) {
        f32x4 v[8];
        #pragma unroll
        for (int kc = 0; kc < 8; ++kc)
            v[kc] = *reinterpret_cast<const f32x4*>(
                eg4 + ((size_t)t * 128 + sl * 32 + c * 8 + kc) * 64 + b);
        const float* wp0 = wpackbase + (size_t)(2 * sl + (c >> 1)) * 1024
                           + (c & 1) * 256;
        #pragma unroll
        for (int kc = 0; kc < 8; ++kc) {
            const float* wp = wp0 + kc * 32;
            const f32x2 elo = __builtin_shufflevector(v[kc], v[kc], 0, 1);
            const f32x2 ehi = __builtin_shufflevector(v[kc], v[kc], 2, 3);
            #pragma unroll
            for (int r = 0; r < 8; ++r) {
                const f32x4 w4 = *reinterpret_cast<const f32x4*>(wp + r * 4);
                const f32x2 wlo = __builtin_shufflevector(w4, w4, 0, 1);
                const f32x2 whi = __builtin_shufflevector(w4, w4, 2, 3);
                PKFMA(eacc2[r], wlo, elo);
                PKFMA(eacc2[r], whi, ehi);
            }
        }
    }
}

// ---------------------------------------------------------------------------
// K1: wave-specialized persistent BiLSTM. 512 WGs (256/dir) x 512 threads.
// ---------------------------------------------------------------------------
__global__ __launch_bounds__(512, 2) void k_lstm(
    const float4* __restrict__ eg4, const float* __restrict__ wpack,
    const float* __restrict__ b_f, const float* __restrict__ b_b,
    float* __restrict__ h_f, float* __restrict__ h_b,
    int* __restrict__ bar)
{
    const int bid = blockIdx.x;
    const int dir = bid >> 8;
    const int wg  = bid & 255;
    float* HH       = dir ? h_b : h_f;
    const float* BS = dir ? b_b : b_f;
    int* flg = bar + (size_t)dir * 262144;  // [step:512][wg:256][half:2]

    const int tid = threadIdx.x;
    const int b   = tid & 63;
    const int wid = __builtin_amdgcn_readfirstlane(tid >> 6);   // 0..7
    const int sl  = wid & 3;                // h-slice or e-slice id

    __shared__ float wlds[4][1024];         // 16 KB h-weights (k=128/slice)
    __shared__ float partb[2][8][8][64];    // 32 KB dbuf partials (h:0-3,e:4-7)

    const float* wpbase = wpack + (size_t)(dir * 256 + wg) * 8192;

    // ---- stage h-weights (sec1) for k in [128sl, 128sl+128) ----
    if (wid < 4) {
        #pragma unroll
        for (int q = 0; q < 2; ++q) {       // ks = 2*sl + q
            const float4* src = reinterpret_cast<const float4*>(
                wpbase + (size_t)(2 * sl + q) * 1024 + 512);
            float4* dst = reinterpret_cast<float4*>(&wlds[sl][q * 512]);
            #pragma unroll
            for (int i = 0; i < 2; ++i)
                dst[i * 64 + b] = src[i * 64 + b];
        }
    }

    // gate lanes: waves 4,5 -> l in [0,128); colL=l&1, gb=l>>1
    const int l    = tid - 256;
    const int colL = l & 1;
    const int gb   = l >> 1;
    float bias4[4] = {0.f, 0.f, 0.f, 0.f};
    float cst = 0.f;
    if (wid == 4 || wid == 5) {
        #pragma unroll
        for (int g = 0; g < 4; ++g) bias4[g] = BS[g * 512 + wg * 2 + colL];
    }

    // ---- e-prologue: eacc for step 0 ----
    f32x2 eacc2[8];
    #pragma unroll
    for (int r = 0; r < 8; ++r) eacc2[r] = (f32x2){0.f, 0.f};
    if (wid >= 4) {
        const int t0 = dir ? 511 : 0;
        edot128(eg4, wpbase, t0, sl, b, eacc2);
    }
    __syncthreads();                        // weights staged

    for (int s = 0; s < 512; ++s) {
        const int t = dir ? (511 - s) : s;

        if (wid < 4) {
            // ---- h-wave: poll own 64 producers, cached h loads, h-dot ----
            f32x2 acc2[8];
            #pragma unroll
            for (int r = 0; r < 8; ++r) acc2[r] = (f32x2){0.f, 0.f};
            if (s > 0) {
                const long long* fp = reinterpret_cast<const long long*>(
                    flg + (size_t)(s - 1) * 512 + sl * 128) + b;
                while (__hip_atomic_load(fp, __ATOMIC_RELAXED,
                                         __HIP_MEMORY_SCOPE_AGENT)
                       != 0x0000000100000001LL)
                    __builtin_amdgcn_s_sleep(1);

                const int tp = dir ? (t + 1) : (t - 1);
                const f32x2* hq = reinterpret_cast<const f32x2*>(HH)
                                  + ((size_t)tp * 256 + sl * 64) * 64 + b;
                #pragma unroll
                for (int c = 0; c < 4; ++c) {
                    f32x2 hv[16];
                    #pragma unroll
                    for (int kq = 0; kq < 16; ++kq)
                        hv[kq] = hq[(size_t)(c * 16 + kq) * 64];
                    #pragma unroll
                    for (int kc = 0; kc < 8; ++kc) {
                        const float* wp = &wlds[sl][c * 256 + kc * 32];
                        #pragma unroll
                        for (int r = 0; r < 8; ++r) {
                            const f32x4 w4 = *reinterpret_cast<const f32x4*>(wp + r * 4);
                            const f32x2 wlo = __builtin_shufflevector(w4, w4, 0, 1);
                            const f32x2 whi = __builtin_shufflevector(w4, w4, 2, 3);
                            PKFMA(acc2[r], wlo, hv[kc * 2]);
                            PKFMA(acc2[r], whi, hv[kc * 2 + 1]);
                        }
                    }
                }
            }
            #pragma unroll
            for (int r = 0; r < 8; ++r)
                partb[s & 1][sl][r][b] = acc2[r][0] + acc2[r][1];
        } else {
            // ---- e-wave: publish last iteration's e-acc as partials ----
            #pragma unroll
            for (int r = 0; r < 8; ++r)
                partb[s & 1][4 + sl][r][b] = eacc2[r][0] + eacc2[r][1];
        }

        __syncthreads();                    // partb[s&1] complete

        // ---- waves 4,5: gates + cstate + coalesced store + flag ----
        if (wid == 4 || wid == 5) {
            float g4[4];
            #pragma unroll
            for (int g = 0; g < 4; ++g) {
                const int r = g * 2 + colL;
                float v = bias4[g];
                #pragma unroll
                for (int w = 0; w < 8; ++w) v += partb[s & 1][w][r][gb];
                g4[g] = v;
            }
            const float si = 1.f / (1.f + expf(-g4[0]));
            const float sf = 1.f / (1.f + expf(-g4[1]));
            const float tg = tanhf(g4[2]);
            const float so = 1.f / (1.f + expf(-g4[3]));
            cst = sf * cst + si * tg;
            const float hval = so * tanhf(cst);
            float* dst = HH + ((size_t)t * 256 + wg) * 128 + l;
            asm volatile("global_store_dword %0, %1, off sc1"
                         :: "v"(dst), "v"(hval) : "memory");
            asm volatile("s_waitcnt vmcnt(0)" ::: "memory");
            if ((l == 0 || l == 64) && s < 511)
                __hip_atomic_store(flg + (size_t)s * 512 + wg * 2 + (l >> 6), 1,
                                   __ATOMIC_RELAXED, __HIP_MEMORY_SCOPE_AGENT);
        }

        // ---- e-waves: e-dot for step s+1 (off the critical chain) ----
        if (wid >= 4 && s < 511) {
            const int tn = dir ? (510 - s) : (s + 1);
            edot128(eg4, wpbase, tn, sl, b, eacc2);
        }
    }
}

// ---------------------------------------------------------------------------
// K2: emissions  em[t][b][tag] = [hf;hb](t,b,:) . W[tag][:] + bias
// h layout [t][c2][b][2]
// ---------------------------------------------------------------------------
__global__ __launch_bounds__(256) void k_em(
    const float* __restrict__ hf, const float* __restrict__ hb,
    const float* __restrict__ Wm, const float* __restrict__ bias,
    float* __restrict__ em)
{
    const int t   = blockIdx.x;
    const int tid = threadIdx.x;
    const int b   = tid & 63;
    const int tg  = tid >> 6;          // 0..3 -> tags [tg*8, tg*8+8)
    __shared__ float Wl[128][33];
    float acc[8] = {};

    for (int ch = 0; ch < 8; ++ch) {
        {
            const int tag = tid >> 3;   // 0..31
            const int kq  = tid & 7;    // 0..7
            const float* src = Wm + (size_t)tag * 1024 + ch * 128 + kq * 16;
            #pragma unroll
            for (int ii = 0; ii < 4; ++ii) {
                const float4 v = *reinterpret_cast<const float4*>(src + ii * 4);
                const int k0 = kq * 16 + ii * 4;
                Wl[k0 + 0][tag] = v.x; Wl[k0 + 1][tag] = v.y;
                Wl[k0 + 2][tag] = v.z; Wl[k0 + 3][tag] = v.w;
            }
        }
        __syncthreads();
        const f32x2* hsrc2 = (ch < 4)
            ? (reinterpret_cast<const f32x2*>(hf) + ((size_t)t * 256 + ch * 64) * 64 + b)
            : (reinterpret_cast<const f32x2*>(hb) + ((size_t)t * 256 + (ch - 4) * 64) * 64 + b);
        #pragma unroll 4
        for (int c2l = 0; c2l < 64; ++c2l) {
            const f32x2 h2 = hsrc2[(size_t)c2l * 64];
            #pragma unroll
            for (int j = 0; j < 2; ++j)
                #pragma unroll
                for (int jt = 0; jt < 8; ++jt)
                    acc[jt] = fmaf(h2[j], Wl[c2l * 2 + j][tg * 8 + jt], acc[jt]);
        }
        __syncthreads();
    }

    #pragma unroll
    for (int jt = 0; jt < 8; ++jt) {
        const int tag = tg * 8 + jt;
        em[((size_t)t * 64 + b) * 32 + tag] = acc[jt] + bias[tag];
    }
}

// ---------------------------------------------------------------------------
// K3: Viterbi forward + backtrace, one wave per batch row.
// ---------------------------------------------------------------------------
__global__ __launch_bounds__(64) void k_vit(
    const float* __restrict__ em, const float* __restrict__ startv,
    const float* __restrict__ endv, const float* __restrict__ trans,
    int* __restrict__ out)
{
    const int b    = blockIdx.x;
    const int lane = threadIdx.x;
    const int c    = lane & 31;
    const bool act = lane < 32;
    __shared__ unsigned char hist[511][32];
    __shared__ int outb[512];

    float tr[32];
    #pragma unroll 8
    for (int p = 0; p < 32; ++p) tr[p] = trans[p * 32 + c];

    float s = act ? (startv[c] + em[(size_t)b * 32 + c]) : -1e30f;

    for (int t = 1; t < 512; ++t) {
        const float emc = act ? em[((size_t)t * 64 + b) * 32 + c] : 0.f;
        float m = -1e30f; int arg = 0;
        #pragma unroll 8
        for (int p = 0; p < 32; ++p) {
            const float v = __shfl(s, p) + tr[p] + emc;   // (s+tr)+em, ref order
            if (v > m) { m = v; arg = p; }                // strict > => first max
        }
        if (act) { s = m; hist[t - 1][c] = (unsigned char)arg; }
    }

    s = act ? (s + endv[c]) : -1e30f;
    int idx = act ? c : 63;
    #pragma unroll
    for (int off = 32; off >= 1; off >>= 1) {
        const float om = __shfl_down(s, off);
        const int   oi = __shfl_down(idx, off);
        if (om > s || (om == s && oi < idx)) { s = om; idx = oi; }
    }
    idx = __shfl(idx, 0);

    if (lane == 0) {
        int tag = idx;
        outb[511] = tag;
        for (int t = 510; t >= 0; --t) { tag = hist[t][tag]; outb[t] = tag; }
    }
    __syncthreads();
    for (int i = lane; i < 512; i += 64) out[(size_t)b * 512 + i] = outb[i];
}

// ---------------------------------------------------------------------------
extern "C" void kernel_launch(void* const* d_in, const int* in_sizes, int n_in,
                              void* d_out, int out_size, void* d_ws, size_t ws_size,
                              hipStream_t stream)
{
    const int*   x      = (const int*)d_in[0];
    const float* emb    = (const float*)d_in[1];
    const float* w_ih_f = (const float*)d_in[2];
    const float* w_hh_f = (const float*)d_in[3];
    const float* b_f    = (const float*)d_in[4];
    const float* w_ih_b = (const float*)d_in[5];
    const float* w_hh_b = (const float*)d_in[6];
    const float* b_b    = (const float*)d_in[7];
    const float* Wm     = (const float*)d_in[8];
    const float* bvec   = (const float*)d_in[9];
    const float* startv = (const float*)d_in[10];
    const float* endv   = (const float*)d_in[11];
    const float* trans  = (const float*)d_in[12];
    int* out = (int*)d_out;

    float* ws    = (float*)d_ws;
    float* eg    = ws;                          // 16,777,216 f32 (64 MB)
    float* h_f   = ws + 16777216;               // 16,777,216 f32
    float* h_b   = ws + 33554432;               // 16,777,216 f32
    float* em    = ws + 50331648;               //  1,048,576 f32
    float* wpack = ws + 51380224;               //  4,194,304 f32 (16 MB)
    int*   bar   = (int*)(ws + 55574528);       //  524,288 ints (2 MB flags)

    const size_t need = (size_t)(55574528 + 524288) * 4;
    if (ws_size < need) {
        fprintf(stderr, "kernel_launch: ws too small: %zu < %zu\n", ws_size, need);
        return;
    }

    (void)hipMemsetAsync(bar, 0, 2097152, stream);
    k_gather<<<dim3(512),   512, 0, stream>>>(x, emb, (float4*)eg);
    k_pack  <<<dim3(16384), 256, 0, stream>>>(w_ih_f, w_hh_f, w_ih_b, w_hh_b, wpack);
    k_lstm  <<<dim3(512),   512, 0, stream>>>((const float4*)eg, wpack, b_f, b_b,
                                              h_f, h_b, bar);
    k_em    <<<dim3(512),   256, 0, stream>>>(h_f, h_b, Wm, bvec, em);
    k_vit   <<<dim3(64),     64, 0, stream>>>(em, startv, endv, trans, out);
}

// Round 20
// 6396.888 us; speedup vs baseline: 1.6798x; 1.6798x over previous
//
#include <hip/hip_runtime.h>
#include <cstdio>
#include <cstdint>

// V=30000, E=512, H=512, T=32, B=64, L=512
// eg layout: [t][e4:128][b:64][4]   (64 MB)
// h  layout: [t][c2:256][b:64][2]   (64 MB per dir)
// em layout: [t][b][tag]            (4 MB)
// wpack: [dir][wg:256][ks:8][sec:2][kc:16][r:8][j:4]  (16 MB)
// R20 = revert to R18 (session best, 6.38 ms): pk-fma both parts, weights in
//   LDS, 512 WGs x 512 thr (2 WGs/CU), per-WG flag-store sync.
// Producer: contiguous 512B dwordx2 sc1 h-store -> vmcnt(0) -> one plain
//   relaxed agent store to flg[dir][step][wg]. Consumer wave ks: 32 lanes
//   poll its exact 32 producers' flags in parallel (one 128B line).
// Structural note (R8-R19 evidence): the remaining ~7.4us/step-pair is
//   cross-XCD coherence latency (store-drain, flag visibility, poll
//   discovery, first-touch h-miss) - an all-reduce per timestep x 512 serial
//   epochs. Barrier/counter/flag/dataflow/wave-specialization variants all
//   land within noise or regress; VALU halving (R16 MFMA) leaves the wall
//   unchanged -> latency-bound floor for this algorithm class on MI355X.

typedef float f32x4 __attribute__((ext_vector_type(4)));
typedef float f32x2 __attribute__((ext_vector_type(2)));

#define PKFMA(ACC, W2, H2) \
    asm("v_pk_fma_f32 %0, %1, %2, %0" : "+v"(ACC) : "v"(W2), "v"(H2))

// ---------------------------------------------------------------------------
// K0: embedding gather -> eg[t][e4][b][4]
// ---------------------------------------------------------------------------
__global__ __launch_bounds__(512) void k_gather(
    const int* __restrict__ x, const float* __restrict__ emb,
    float4* __restrict__ eg4)
{
    const int t   = blockIdx.x;
    const int tid = threadIdx.x;
    __shared__ int xv[64];
    if (tid < 64) xv[tid] = x[tid * 512 + t];
    __syncthreads();
    #pragma unroll
    for (int i = 0; i < 16; ++i) {
        const int flat = i * 512 + tid;       // 0..8191
        const int b  = flat & 63;
        const int e4 = flat >> 6;             // 0..127
        const float4 v = *reinterpret_cast<const float4*>(
            emb + (size_t)xv[b] * 512 + e4 * 4);
        eg4[((size_t)t * 128 + e4) * 64 + b] = v;
    }
}

// ---------------------------------------------------------------------------
// K0b: pack weights: [dir][wg:256][ks:8][sec:2][kc:16][r:8][j:4]
// ---------------------------------------------------------------------------
__global__ __launch_bounds__(256) void k_pack(
    const float* __restrict__ wih_f, const float* __restrict__ whh_f,
    const float* __restrict__ wih_b, const float* __restrict__ whh_b,
    float* __restrict__ wpack)
{
    const int i = blockIdx.x * 256 + threadIdx.x;   // 0 .. 4194303
    const int j   = i & 3;
    const int r   = (i >> 2) & 7;
    const int kc  = (i >> 5) & 15;
    const int sec = (i >> 9) & 1;
    const int ks  = (i >> 10) & 7;
    const int wg  = (i >> 13) & 255;
    const int dir = (i >> 21) & 1;
    const int k   = ks * 64 + kc * 4 + j;           // 0..511
    const int g   = r >> 1, colL = r & 1;
    const int rg  = g * 512 + wg * 2 + colL;        // global gate row
    const float* wih = dir ? wih_b : wih_f;
    const float* whh = dir ? whh_b : whh_f;
    const float v = sec ? whh[(size_t)rg * 512 + k] : wih[(size_t)rg * 512 + k];
    wpack[i] = v;
}

// ---------------------------------------------------------------------------
// K1: persistent BiLSTM recurrence. 512 WGs (256/dir) x 512 threads.
// WG owns 2 h-cols (8 gate rows). lane = b, wave = k-slice (split-k x8).
// All weights in LDS; packed-f32 FMA. Per-wave flag-based dataflow sync.
// ---------------------------------------------------------------------------
__global__ __launch_bounds__(512, 2) void k_lstm(
    const float4* __restrict__ eg4, const float* __restrict__ wpack,
    const float* __restrict__ b_f, const float* __restrict__ b_b,
    float* __restrict__ h_f, float* __restrict__ h_b,
    int* __restrict__ bar)
{
    const int bid = blockIdx.x;
    const int dir = bid >> 8;
    const int wg  = bid & 255;
    float* HH       = dir ? h_b : h_f;
    const float* BS = dir ? b_b : b_f;
    int* flg = bar + (size_t)dir * 131072;  // [step:512][wg:256] ints

    const int tid = threadIdx.x;
    const int b   = tid & 63;
    const int ks  = __builtin_amdgcn_readfirstlane(tid >> 6);   // 0..7

    __shared__ float wlds[8][1024];     // 32 KB: per-wave [sec0:512|sec1:512]
    __shared__ float partb[8 * 8 * 64]; // 16 KB split-k exchange
    __shared__ float hlds[64][2];       // h staging for coalesced store

    // ---- stage this wave's weights into LDS once (1024 f32) ----
    {
        const float4* src = reinterpret_cast<const float4*>(
            wpack + (size_t)((dir * 256 + wg) * 8 + ks) * 1024);
        float4* dst = reinterpret_cast<float4*>(&wlds[ks][0]);
        #pragma unroll
        for (int i = 0; i < 4; ++i)
            dst[i * 64 + b] = src[i * 64 + b];
    }

    const int colL = (tid >> 6) & 1;    // gate-phase col (tid<128)
    float bias4[4] = {0.f, 0.f, 0.f, 0.f};
    if (tid < 128) {
        #pragma unroll
        for (int g = 0; g < 4; ++g) bias4[g] = BS[g * 512 + wg * 2 + colL];
    }
    float cst = 0.f;
    __syncthreads();                    // wlds ready

    const float* wl = &wlds[ks][0];

    // packed e-accumulator (lo=even-k, hi=odd-k)
    f32x2 eacc2[8];
    #pragma unroll
    for (int r = 0; r < 8; ++r) eacc2[r] = (f32x2){0.f, 0.f};

    // prologue: e-part for step 0
    {
        const int t0 = dir ? 511 : 0;
        const float4* ep = eg4 + ((size_t)t0 * 128 + ks * 16) * 64 + b;
        #pragma unroll
        for (int half = 0; half < 2; ++half) {
            f32x4 v[8];
            #pragma unroll
            for (int kc = 0; kc < 8; ++kc)
                v[kc] = *reinterpret_cast<const f32x4*>(ep + (size_t)(half * 8 + kc) * 64);
            #pragma unroll
            for (int kc = 0; kc < 8; ++kc) {
                const float* wp = wl + (half * 8 + kc) * 32;
                const f32x2 elo = __builtin_shufflevector(v[kc], v[kc], 0, 1);
                const f32x2 ehi = __builtin_shufflevector(v[kc], v[kc], 2, 3);
                #pragma unroll
                for (int r = 0; r < 8; ++r) {
                    const f32x4 w4 = *reinterpret_cast<const f32x4*>(wp + r * 4);
                    const f32x2 wlo = __builtin_shufflevector(w4, w4, 0, 1);
                    const f32x2 whi = __builtin_shufflevector(w4, w4, 2, 3);
                    PKFMA(eacc2[r], wlo, elo);
                    PKFMA(eacc2[r], whi, ehi);
                }
            }
        }
    }

    for (int s = 0; s < 512; ++s) {
        const int t = dir ? (511 - s) : s;
        f32x2 acc2[8];
        #pragma unroll
        for (int r = 0; r < 8; ++r) acc2[r] = eacc2[r];

        // ---- per-wave wait: 32 lanes poll the wave's 32 producers' flags ----
        if (s > 0) {
            const int* fp = flg + (size_t)(s - 1) * 256 + ks * 32 + (b & 31);
            while (__hip_atomic_load(fp, __ATOMIC_RELAXED,
                                     __HIP_MEMORY_SCOPE_AGENT) == 0)
                __builtin_amdgcn_s_sleep(1);

            const int tp = dir ? (t + 1) : (t - 1);
            const f32x2* hq = reinterpret_cast<const f32x2*>(HH)
                              + ((size_t)tp * 256 + ks * 32) * 64 + b;
            #pragma unroll
            for (int half = 0; half < 2; ++half) {
                f32x2 hv[16];
                #pragma unroll
                for (int kq = 0; kq < 16; ++kq)
                    hv[kq] = hq[(size_t)(half * 16 + kq) * 64];
                #pragma unroll
                for (int kc = 0; kc < 8; ++kc) {
                    const float* wp = wl + 512 + (half * 8 + kc) * 32;
                    #pragma unroll
                    for (int r = 0; r < 8; ++r) {
                        const f32x4 w4 = *reinterpret_cast<const f32x4*>(wp + r * 4);
                        const f32x2 wlo = __builtin_shufflevector(w4, w4, 0, 1);
                        const f32x2 whi = __builtin_shufflevector(w4, w4, 2, 3);
                        PKFMA(acc2[r], wlo, hv[kc * 2]);
                        PKFMA(acc2[r], whi, hv[kc * 2 + 1]);
                    }
                }
            }
        }

        // ---- split-k reduce (horizontal add once per row) ----
        #pragma unroll
        for (int r = 0; r < 8; ++r)
            partb[(ks * 8 + r) * 64 + b] = acc2[r][0] + acc2[r][1];
        __syncthreads();                 // sync1: part ready

        // ---- gates (tid<128: colL x b) ----
        if (tid < 128) {
            float g4[4];
            #pragma unroll
            for (int g = 0; g < 4; ++g) {
                const int r = g * 2 + colL;
                float v = bias4[g];
                #pragma unroll
                for (int w = 0; w < 8; ++w) v += partb[(w * 8 + r) * 64 + b];
                g4[g] = v;
            }
            const float si = 1.f / (1.f + expf(-g4[0]));
            const float sf = 1.f / (1.f + expf(-g4[1]));
            const float tg = tanhf(g4[2]);
            const float so = 1.f / (1.f + expf(-g4[3]));
            cst = sf * cst + si * tg;
            hlds[b][colL] = so * tanhf(cst);
        }
        __syncthreads();                 // sync2: hlds ready, part consumed

        // ---- wave0: contiguous sc1 dwordx2 store, drain, flag store ----
        if (tid < 64) {
            f32x2 o;
            o[0] = hlds[tid][0]; o[1] = hlds[tid][1];
            float* dst = HH + (((size_t)t * 256 + wg) * 64 + tid) * 2;
            asm volatile("global_store_dwordx2 %0, %1, off sc1"
                         :: "v"(dst), "v"(o) : "memory");
            asm volatile("s_waitcnt vmcnt(0)" ::: "memory");
            if (tid == 0 && s < 511)
                __hip_atomic_store(flg + (size_t)s * 256 + wg, 1,
                                   __ATOMIC_RELAXED, __HIP_MEMORY_SCOPE_AGENT);
        }

        // ---- e-part for step s+1 (LDS weights; off critical path) ----
        if (s < 511) {
            const int tn = dir ? (t - 1) : (t + 1);
            const float4* ep = eg4 + ((size_t)tn * 128 + ks * 16) * 64 + b;
            #pragma unroll
            for (int r = 0; r < 8; ++r) eacc2[r] = (f32x2){0.f, 0.f};
            #pragma unroll
            for (int half = 0; half < 2; ++half) {
                f32x4 v[8];
                #pragma unroll
                for (int kc = 0; kc < 8; ++kc)
                    v[kc] = *reinterpret_cast<const f32x4*>(ep + (size_t)(half * 8 + kc) * 64);
                #pragma unroll
                for (int kc = 0; kc < 8; ++kc) {
                    const float* wp = wl + (half * 8 + kc) * 32;
                    const f32x2 elo = __builtin_shufflevector(v[kc], v[kc], 0, 1);
                    const f32x2 ehi = __builtin_shufflevector(v[kc], v[kc], 2, 3);
                    #pragma unroll
                    for (int r = 0; r < 8; ++r) {
                        const f32x4 w4 = *reinterpret_cast<const f32x4*>(wp + r * 4);
                        const f32x2 wlo = __builtin_shufflevector(w4, w4, 0, 1);
                        const f32x2 whi = __builtin_shufflevector(w4, w4, 2, 3);
                        PKFMA(eacc2[r], wlo, elo);
                        PKFMA(eacc2[r], whi, ehi);
                    }
                }
            }
        }
    }
}

// ---------------------------------------------------------------------------
// K2: emissions  em[t][b][tag] = [hf;hb](t,b,:) . W[tag][:] + bias
// h layout [t][c2][b][2]
// ---------------------------------------------------------------------------
__global__ __launch_bounds__(256) void k_em(
    const float* __restrict__ hf, const float* __restrict__ hb,
    const float* __restrict__ Wm, const float* __restrict__ bias,
    float* __restrict__ em)
{
    const int t   = blockIdx.x;
    const int tid = threadIdx.x;
    const int b   = tid & 63;
    const int tg  = tid >> 6;          // 0..3 -> tags [tg*8, tg*8+8)
    __shared__ float Wl[128][33];
    float acc[8] = {};

    for (int ch = 0; ch < 8; ++ch) {
        {
            const int tag = tid >> 3;   // 0..31
            const int kq  = tid & 7;    // 0..7
            const float* src = Wm + (size_t)tag * 1024 + ch * 128 + kq * 16;
            #pragma unroll
            for (int ii = 0; ii < 4; ++ii) {
                const float4 v = *reinterpret_cast<const float4*>(src + ii * 4);
                const int k0 = kq * 16 + ii * 4;
                Wl[k0 + 0][tag] = v.x; Wl[k0 + 1][tag] = v.y;
                Wl[k0 + 2][tag] = v.z; Wl[k0 + 3][tag] = v.w;
            }
        }
        __syncthreads();
        const f32x2* hsrc2 = (ch < 4)
            ? (reinterpret_cast<const f32x2*>(hf) + ((size_t)t * 256 + ch * 64) * 64 + b)
            : (reinterpret_cast<const f32x2*>(hb) + ((size_t)t * 256 + (ch - 4) * 64) * 64 + b);
        #pragma unroll 4
        for (int c2l = 0; c2l < 64; ++c2l) {
            const f32x2 h2 = hsrc2[(size_t)c2l * 64];
            #pragma unroll
            for (int j = 0; j < 2; ++j)
                #pragma unroll
                for (int jt = 0; jt < 8; ++jt)
                    acc[jt] = fmaf(h2[j], Wl[c2l * 2 + j][tg * 8 + jt], acc[jt]);
        }
        __syncthreads();
    }

    #pragma unroll
    for (int jt = 0; jt < 8; ++jt) {
        const int tag = tg * 8 + jt;
        em[((size_t)t * 64 + b) * 32 + tag] = acc[jt] + bias[tag];
    }
}

// ---------------------------------------------------------------------------
// K3: Viterbi forward + backtrace, one wave per batch row.
// ---------------------------------------------------------------------------
__global__ __launch_bounds__(64) void k_vit(
    const float* __restrict__ em, const float* __restrict__ startv,
    const float* __restrict__ endv, const float* __restrict__ trans,
    int* __restrict__ out)
{
    const int b    = blockIdx.x;
    const int lane = threadIdx.x;
    const int c    = lane & 31;
    const bool act = lane < 32;
    __shared__ unsigned char hist[511][32];
    __shared__ int outb[512];

    float tr[32];
    #pragma unroll 8
    for (int p = 0; p < 32; ++p) tr[p] = trans[p * 32 + c];

    float s = act ? (startv[c] + em[(size_t)b * 32 + c]) : -1e30f;

    for (int t = 1; t < 512; ++t) {
        const float emc = act ? em[((size_t)t * 64 + b) * 32 + c] : 0.f;
        float m = -1e30f; int arg = 0;
        #pragma unroll 8
        for (int p = 0; p < 32; ++p) {
            const float v = __shfl(s, p) + tr[p] + emc;   // (s+tr)+em, ref order
            if (v > m) { m = v; arg = p; }                // strict > => first max
        }
        if (act) { s = m; hist[t - 1][c] = (unsigned char)arg; }
    }

    s = act ? (s + endv[c]) : -1e30f;
    int idx = act ? c : 63;
    #pragma unroll
    for (int off = 32; off >= 1; off >>= 1) {
        const float om = __shfl_down(s, off);
        const int   oi = __shfl_down(idx, off);
        if (om > s || (om == s && oi < idx)) { s = om; idx = oi; }
    }
    idx = __shfl(idx, 0);

    if (lane == 0) {
        int tag = idx;
        outb[511] = tag;
        for (int t = 510; t >= 0; --t) { tag = hist[t][tag]; outb[t] = tag; }
    }
    __syncthreads();
    for (int i = lane; i < 512; i += 64) out[(size_t)b * 512 + i] = outb[i];
}

// ---------------------------------------------------------------------------
extern "C" void kernel_launch(void* const* d_in, const int* in_sizes, int n_in,
                              void* d_out, int out_size, void* d_ws, size_t ws_size,
                              hipStream_t stream)
{
    const int*   x      = (const int*)d_in[0];
    const float* emb    = (const float*)d_in[1];
    const float* w_ih_f = (const float*)d_in[2];
    const float* w_hh_f = (const float*)d_in[3];
    const float* b_f    = (const float*)d_in[4];
    const float* w_ih_b = (const float*)d_in[5];
    const float* w_hh_b = (const float*)d_in[6];
    const float* b_b    = (const float*)d_in[7];
    const float* Wm     = (const float*)d_in[8];
    const float* bvec   = (const float*)d_in[9];
    const float* startv = (const float*)d_in[10];
    const float* endv   = (const float*)d_in[11];
    const float* trans  = (const float*)d_in[12];
    int* out = (int*)d_out;

    float* ws    = (float*)d_ws;
    float* eg    = ws;                          // 16,777,216 f32 (64 MB)
    float* h_f   = ws + 16777216;               // 16,777,216 f32
    float* h_b   = ws + 33554432;               // 16,777,216 f32
    float* em    = ws + 50331648;               //  1,048,576 f32
    float* wpack = ws + 51380224;               //  4,194,304 f32 (16 MB)
    int*   bar   = (int*)(ws + 55574528);       //  262,144 ints (1 MB flags)

    const size_t need = (size_t)(55574528 + 262144) * 4;
    if (ws_size < need) {
        fprintf(stderr, "kernel_launch: ws too small: %zu < %zu\n", ws_size, need);
        return;
    }

    (void)hipMemsetAsync(bar, 0, 1048576, stream);
    k_gather<<<dim3(512),   512, 0, stream>>>(x, emb, (float4*)eg);
    k_pack  <<<dim3(16384), 256, 0, stream>>>(w_ih_f, w_hh_f, w_ih_b, w_hh_b, wpack);
    k_lstm  <<<dim3(512),   512, 0, stream>>>((const float4*)eg, wpack, b_f, b_b,
                                              h_f, h_b, bar);
    k_em    <<<dim3(512),   256, 0, stream>>>(h_f, h_b, Wm, bvec, em);
    k_vit   <<<dim3(64),     64, 0, stream>>>(em, startv, endv, trans, out);
}